// Round 1
// baseline (5974.659 us; speedup 1.0000x reference)
//
#include <hip/hip_runtime.h>
#include <math.h>

// Problem constants
#define Bb 2
#define Tt 1024
#define Ss 1024
#define Dd 512
#define Hh 8
#define DHh 64
#define Ll 4
#define Ee 8
#define KK 2
#define FFf 2048
#define Mm 2048        // B*T token rows
#define NPp 4096       // Mm*KK token-expert pairs
#define EPSF 1e-5f
#define DD_ (Dd*Dd)

// ---------------------------------------------------------------------------
// Embedding + positional
// ---------------------------------------------------------------------------
__global__ void embed_kernel(const int* __restrict__ ids,
                             const float* __restrict__ emb,
                             const float* __restrict__ pos,
                             float* __restrict__ Y) {
  int m = blockIdx.x;
  int t = m % Tt;
  int id = ids[m];
  for (int d = threadIdx.x; d < Dd; d += 256)
    Y[(size_t)m * Dd + d] = emb[(size_t)id * Dd + d] + pos[(size_t)t * Dd + d];
}

// ---------------------------------------------------------------------------
// Generic fp32 tiled GEMM: C[M,N] = A[M,K] @ W[K,N] + bias[N]
// grid: (N/64, M/64); 256 threads; M,N,K multiples of 64/16.
// ---------------------------------------------------------------------------
__global__ __launch_bounds__(256)
void gemm_bias(const float* __restrict__ A, const float* __restrict__ W,
               const float* __restrict__ bias, float* __restrict__ C,
               int K, int N) {
  __shared__ float As[16][68];   // [k][m], padded for b128-aligned reads
  __shared__ float Bs[16][64];   // [k][n]
  int m0 = blockIdx.y * 64, n0 = blockIdx.x * 64;
  int tid = threadIdx.x;
  int tx = tid & 15, ty = tid >> 4;
  float acc[4][4] = {};
  for (int kc = 0; kc < K; kc += 16) {
    {
      int r = tid >> 2, c4 = tid & 3;
      float4 av = *reinterpret_cast<const float4*>(&A[(size_t)(m0 + r) * K + kc + c4 * 4]);
      As[c4 * 4 + 0][r] = av.x; As[c4 * 4 + 1][r] = av.y;
      As[c4 * 4 + 2][r] = av.z; As[c4 * 4 + 3][r] = av.w;
      int rb = tid >> 4, cb = tid & 15;
      *reinterpret_cast<float4*>(&Bs[rb][cb * 4]) =
          *reinterpret_cast<const float4*>(&W[(size_t)(kc + rb) * N + n0 + cb * 4]);
    }
    __syncthreads();
#pragma unroll
    for (int kk = 0; kk < 16; ++kk) {
      float4 a4 = *reinterpret_cast<const float4*>(&As[kk][ty * 4]);
      float4 b4 = *reinterpret_cast<const float4*>(&Bs[kk][tx * 4]);
      float a[4] = {a4.x, a4.y, a4.z, a4.w};
      float b[4] = {b4.x, b4.y, b4.z, b4.w};
#pragma unroll
      for (int i = 0; i < 4; i++)
#pragma unroll
        for (int j = 0; j < 4; j++) acc[i][j] += a[i] * b[j];
    }
    __syncthreads();
  }
#pragma unroll
  for (int i = 0; i < 4; i++) {
    int m = m0 + ty * 4 + i;
#pragma unroll
    for (int j = 0; j < 4; j++) {
      int n = n0 + tx * 4 + j;
      C[(size_t)m * N + n] = acc[i][j] + bias[n];
    }
  }
}

// ---------------------------------------------------------------------------
// Flash-style attention. One wave per query row, 4 rows per block.
// Q,O rows: b*Tt + t, head columns h*64..h*64+63. K/V rows: b*nK + s.
// grid: (B*H, T/4)
// ---------------------------------------------------------------------------
__global__ __launch_bounds__(256)
void attn_kernel(const float* __restrict__ Q, const float* __restrict__ Kb,
                 const float* __restrict__ Vb, float* __restrict__ O,
                 const int* __restrict__ amask, int causal, int nK) {
  int bh = blockIdx.x;
  int b = bh >> 3, h = bh & 7;
  int wv = threadIdx.x >> 6, lane = threadIdx.x & 63;
  int t = blockIdx.y * 4 + wv;

  __shared__ float Ks[64][65];
  __shared__ float Vs[64][65];
  __shared__ float qs[4][64];
  __shared__ float ps[4][64];

  qs[wv][lane] = Q[((size_t)(b * Tt + t)) * Dd + h * DHh + lane];

  float m = -1e30f, l = 0.f, o = 0.f;
  int lim = causal ? (blockIdx.y * 4 + 4) : nK;  // same tile count for all 4 waves
  int NT = (lim + 63) >> 6;
  size_t krow0 = (size_t)b * nK;

  for (int kt = 0; kt < NT; ++kt) {
    __syncthreads();
    for (int i = threadIdx.x; i < 64 * 64; i += 256) {
      int r = i >> 6, c = i & 63;
      size_t gr = (krow0 + kt * 64 + r) * Dd + h * DHh + c;
      Ks[r][c] = Kb[gr];
      Vs[r][c] = Vb[gr];
    }
    __syncthreads();

    int kj = kt * 64 + lane;
    float s = -1e9f;
    bool valid = (kj < nK) && (!causal || kj <= t);
    if (valid && amask) valid = (amask[b * nK + kj] != 0);
    if (valid) {
      float acc = 0.f;
#pragma unroll
      for (int d = 0; d < 64; ++d) acc += qs[wv][d] * Ks[lane][d];
      s = acc * 0.125f;  // 1/sqrt(64)
    }
    float mt = s;
#pragma unroll
    for (int off = 32; off; off >>= 1) mt = fmaxf(mt, __shfl_xor(mt, off, 64));
    float mnew = fmaxf(m, mt);
    float p = expf(s - mnew);
    float alpha = expf(m - mnew);
    float psum = p;
#pragma unroll
    for (int off = 32; off; off >>= 1) psum += __shfl_xor(psum, off, 64);
    l = l * alpha + psum;
    m = mnew;
    ps[wv][lane] = p;
    __syncthreads();
    float od = 0.f;
#pragma unroll
    for (int j = 0; j < 64; ++j) od += ps[wv][j] * Vs[j][lane];
    o = o * alpha + od;
  }
  O[((size_t)(b * Tt + t)) * Dd + h * DHh + lane] = o / l;
}

// ---------------------------------------------------------------------------
// Residual add + LayerNorm (in place on Y). One block per row.
// ---------------------------------------------------------------------------
__global__ __launch_bounds__(256)
void add_ln_kernel(float* __restrict__ Y, const float* __restrict__ Aadd,
                   const float* __restrict__ g, const float* __restrict__ bb) {
  int tid = threadIdx.x;
  size_t base = (size_t)blockIdx.x * Dd;
  __shared__ float red[256];
  __shared__ float mu_s, rs_s;
  float x0 = Y[base + tid] + Aadd[base + tid];
  float x1 = Y[base + 256 + tid] + Aadd[base + 256 + tid];
  red[tid] = x0 + x1; __syncthreads();
  for (int s2 = 128; s2 > 0; s2 >>= 1) { if (tid < s2) red[tid] += red[tid + s2]; __syncthreads(); }
  if (tid == 0) mu_s = red[0] / (float)Dd;
  __syncthreads();
  float mu = mu_s;
  float d0 = x0 - mu, d1 = x1 - mu;
  red[tid] = d0 * d0 + d1 * d1; __syncthreads();
  for (int s2 = 128; s2 > 0; s2 >>= 1) { if (tid < s2) red[tid] += red[tid + s2]; __syncthreads(); }
  if (tid == 0) rs_s = rsqrtf(red[0] / (float)Dd + EPSF);
  __syncthreads();
  float rs = rs_s;
  Y[base + tid]       = d0 * rs * g[tid] + bb[tid];
  Y[base + 256 + tid] = d1 * rs * g[256 + tid] + bb[256 + tid];
}

// Combine MoE pair outputs + residual + LayerNorm
__global__ __launch_bounds__(256)
void combine_ln_kernel(float* __restrict__ Y, const float* __restrict__ pout,
                       const int* __restrict__ slot,
                       const float* __restrict__ g, const float* __restrict__ bb) {
  int tid = threadIdx.x;
  int m = blockIdx.x;
  size_t base = (size_t)m * Dd;
  int s0 = slot[m * 2 + 0], s1 = slot[m * 2 + 1];
  __shared__ float red[256];
  __shared__ float mu_s, rs_s;
  float x0 = Y[base + tid] + pout[(size_t)s0 * Dd + tid] + pout[(size_t)s1 * Dd + tid];
  float x1 = Y[base + 256 + tid] + pout[(size_t)s0 * Dd + 256 + tid] + pout[(size_t)s1 * Dd + 256 + tid];
  red[tid] = x0 + x1; __syncthreads();
  for (int s2 = 128; s2 > 0; s2 >>= 1) { if (tid < s2) red[tid] += red[tid + s2]; __syncthreads(); }
  if (tid == 0) mu_s = red[0] / (float)Dd;
  __syncthreads();
  float mu = mu_s;
  float d0 = x0 - mu, d1 = x1 - mu;
  red[tid] = d0 * d0 + d1 * d1; __syncthreads();
  for (int s2 = 128; s2 > 0; s2 >>= 1) { if (tid < s2) red[tid] += red[tid + s2]; __syncthreads(); }
  if (tid == 0) rs_s = rsqrtf(red[0] / (float)Dd + EPSF);
  __syncthreads();
  float rs = rs_s;
  Y[base + tid]       = d0 * rs * g[tid] + bb[tid];
  Y[base + 256 + tid] = d1 * rs * g[256 + tid] + bb[256 + tid];
}

// ---------------------------------------------------------------------------
// Router: probs, top-2, renormalized gates, lb statistics
// ---------------------------------------------------------------------------
__global__ void zero_small_kernel(int* cnt, float* sumP) {
  int t = threadIdx.x;
  if (t < Ee) { cnt[t] = 0; sumP[t] = 0.f; }
}

__global__ __launch_bounds__(256)
void router_kernel(const float* __restrict__ Y, const float* __restrict__ rw,
                   const float* __restrict__ rb, float* __restrict__ gates,
                   int* __restrict__ topi, int* __restrict__ cnt,
                   float* __restrict__ sumP) {
  int wv = threadIdx.x >> 6, lane = threadIdx.x & 63;
  int m = blockIdx.x * 4 + wv;
  const float* yr = Y + (size_t)m * Dd;
  float acc[Ee];
#pragma unroll
  for (int e = 0; e < Ee; e++) acc[e] = 0.f;
  for (int d = lane; d < Dd; d += 64) {
    float yv = yr[d];
#pragma unroll
    for (int e = 0; e < Ee; e++) acc[e] += yv * rw[d * Ee + e];
  }
#pragma unroll
  for (int e = 0; e < Ee; e++)
    for (int off = 32; off; off >>= 1) acc[e] += __shfl_xor(acc[e], off, 64);
  if (lane == 0) {
    float p[Ee];
    float mx = -1e30f;
    for (int e = 0; e < Ee; e++) { p[e] = acc[e] + rb[e]; mx = fmaxf(mx, p[e]); }
    float ssum = 0.f;
    for (int e = 0; e < Ee; e++) { p[e] = expf(p[e] - mx); ssum += p[e]; }
    for (int e = 0; e < Ee; e++) p[e] /= ssum;
    int i1 = 0;
    for (int e = 1; e < Ee; e++) if (p[e] > p[i1]) i1 = e;
    int i2 = (i1 == 0) ? 1 : 0;
    for (int e = 0; e < Ee; e++) if (e != i1 && p[e] > p[i2]) i2 = e;
    float gs = p[i1] + p[i2];
    gates[m * 2 + 0] = p[i1] / gs;
    gates[m * 2 + 1] = p[i2] / gs;
    topi[m * 2 + 0] = i1;
    topi[m * 2 + 1] = i2;
    atomicAdd(&cnt[i1], 1);
    atomicAdd(&cnt[i2], 1);
    for (int e = 0; e < Ee; e++) atomicAdd(&sumP[e], p[e]);
  }
}

__global__ void prefix_lb_kernel(const int* __restrict__ cnt, int* __restrict__ offs,
                                 int* __restrict__ fill, const float* __restrict__ sumP,
                                 float* __restrict__ lb_acc) {
  if (threadIdx.x == 0) {
    int run = 0;
    float lb = 0.f;
    for (int e = 0; e < Ee; e++) {
      offs[e] = run; run += cnt[e];
      fill[e] = 0;
      lb += ((float)cnt[e] / (float)Mm) * (sumP[e] / (float)Mm);
    }
    *lb_acc += (float)Ee * lb;
  }
}

__global__ __launch_bounds__(256)
void scatter_kernel(const int* __restrict__ topi, const float* __restrict__ gates,
                    const int* __restrict__ offs, int* __restrict__ fill,
                    int* __restrict__ pair_tok, float* __restrict__ pair_gate,
                    int* __restrict__ slot) {
  int m = blockIdx.x * 256 + threadIdx.x;
  if (m >= Mm) return;
  for (int k2 = 0; k2 < 2; k2++) {
    int e = topi[m * 2 + k2];
    int pos = atomicAdd(&fill[e], 1);
    int idx = offs[e] + pos;
    pair_tok[idx] = m;
    pair_gate[idx] = gates[m * 2 + k2];
    slot[m * 2 + k2] = idx;
  }
}

// ---------------------------------------------------------------------------
// Expert GEMM1: H[p,:] = relu(Y[tok(p),:] @ W1[e] + b1[e])
// grid: (FF/64, NP/64, E); early-exit on count.
// ---------------------------------------------------------------------------
__global__ __launch_bounds__(256)
void expert_gemm1(const float* __restrict__ Y, const float* __restrict__ w1,
                  const float* __restrict__ b1, const int* __restrict__ pair_tok,
                  const int* __restrict__ offs, const int* __restrict__ cnt,
                  float* __restrict__ Hout) {
  int e = blockIdx.z;
  int ne = cnt[e];
  int pt = blockIdx.y;
  if (pt * 64 >= ne) return;
  int base = offs[e] + pt * 64;
  int rem = ne - pt * 64;
  int n0 = blockIdx.x * 64;
  const float* W = w1 + (size_t)e * Dd * FFf;
  const float* bias = b1 + (size_t)e * FFf;

  __shared__ float As[16][68];
  __shared__ float Bs[16][64];
  __shared__ int toks[64];
  int tid = threadIdx.x;
  if (tid < 64) toks[tid] = (tid < rem) ? pair_tok[base + tid] : pair_tok[base];
  __syncthreads();

  int tx = tid & 15, ty = tid >> 4;
  float acc[4][4] = {};
  for (int kc = 0; kc < Dd; kc += 16) {
    {
      int r = tid >> 2, c4 = tid & 3;
      float4 av = *reinterpret_cast<const float4*>(&Y[(size_t)toks[r] * Dd + kc + c4 * 4]);
      As[c4 * 4 + 0][r] = av.x; As[c4 * 4 + 1][r] = av.y;
      As[c4 * 4 + 2][r] = av.z; As[c4 * 4 + 3][r] = av.w;
      int rb = tid >> 4, cb = tid & 15;
      *reinterpret_cast<float4*>(&Bs[rb][cb * 4]) =
          *reinterpret_cast<const float4*>(&W[(size_t)(kc + rb) * FFf + n0 + cb * 4]);
    }
    __syncthreads();
#pragma unroll
    for (int kk = 0; kk < 16; ++kk) {
      float4 a4 = *reinterpret_cast<const float4*>(&As[kk][ty * 4]);
      float4 b4 = *reinterpret_cast<const float4*>(&Bs[kk][tx * 4]);
      float a[4] = {a4.x, a4.y, a4.z, a4.w};
      float b[4] = {b4.x, b4.y, b4.z, b4.w};
#pragma unroll
      for (int i = 0; i < 4; i++)
#pragma unroll
        for (int j = 0; j < 4; j++) acc[i][j] += a[i] * b[j];
    }
    __syncthreads();
  }
#pragma unroll
  for (int i = 0; i < 4; i++) {
    int r = ty * 4 + i;
    if (r < rem) {
#pragma unroll
      for (int j = 0; j < 4; j++) {
        int n = n0 + tx * 4 + j;
        Hout[(size_t)(base + r) * FFf + n] = fmaxf(acc[i][j] + bias[n], 0.f);
      }
    }
  }
}

// ---------------------------------------------------------------------------
// Expert GEMM2: pout[p,:] = gate(p) * (H[p,:] @ W2[e] + b2[e])
// grid: (D/64, NP/64, E)
// ---------------------------------------------------------------------------
__global__ __launch_bounds__(256)
void expert_gemm2(const float* __restrict__ Hin, const float* __restrict__ w2,
                  const float* __restrict__ b2, const float* __restrict__ pair_gate,
                  const int* __restrict__ offs, const int* __restrict__ cnt,
                  float* __restrict__ pout) {
  int e = blockIdx.z;
  int ne = cnt[e];
  int pt = blockIdx.y;
  if (pt * 64 >= ne) return;
  int base = offs[e] + pt * 64;
  int rem = ne - pt * 64;
  int n0 = blockIdx.x * 64;
  const float* W = w2 + (size_t)e * FFf * Dd;
  const float* bias = b2 + (size_t)e * Dd;

  __shared__ float As[16][68];
  __shared__ float Bs[16][64];
  int tid = threadIdx.x;
  int tx = tid & 15, ty = tid >> 4;
  float acc[4][4] = {};
  for (int kc = 0; kc < FFf; kc += 16) {
    {
      int r = tid >> 2, c4 = tid & 3;
      float4 av = *reinterpret_cast<const float4*>(&Hin[(size_t)(base + r) * FFf + kc + c4 * 4]);
      As[c4 * 4 + 0][r] = av.x; As[c4 * 4 + 1][r] = av.y;
      As[c4 * 4 + 2][r] = av.z; As[c4 * 4 + 3][r] = av.w;
      int rb = tid >> 4, cb = tid & 15;
      *reinterpret_cast<float4*>(&Bs[rb][cb * 4]) =
          *reinterpret_cast<const float4*>(&W[(size_t)(kc + rb) * Dd + n0 + cb * 4]);
    }
    __syncthreads();
#pragma unroll
    for (int kk = 0; kk < 16; ++kk) {
      float4 a4 = *reinterpret_cast<const float4*>(&As[kk][ty * 4]);
      float4 b4 = *reinterpret_cast<const float4*>(&Bs[kk][tx * 4]);
      float a[4] = {a4.x, a4.y, a4.z, a4.w};
      float b[4] = {b4.x, b4.y, b4.z, b4.w};
#pragma unroll
      for (int i = 0; i < 4; i++)
#pragma unroll
        for (int j = 0; j < 4; j++) acc[i][j] += a[i] * b[j];
    }
    __syncthreads();
  }
#pragma unroll
  for (int i = 0; i < 4; i++) {
    int r = ty * 4 + i;
    if (r < rem) {
      float gate = pair_gate[base + r];
#pragma unroll
      for (int j = 0; j < 4; j++) {
        int n = n0 + tx * 4 + j;
        pout[(size_t)(base + r) * Dd + n] = gate * (acc[i][j] + bias[n]);
      }
    }
  }
}

// ---------------------------------------------------------------------------
__global__ void init_lb_kernel(float* lb_acc) {
  if (threadIdx.x == 0) *lb_acc = 0.f;
}

__global__ void finalize_kernel(const float* __restrict__ Y,
                                const float* __restrict__ lb_acc,
                                float* __restrict__ out) {
  size_t i = (size_t)blockIdx.x * 256 + threadIdx.x;
  const size_t n = (size_t)Mm * Dd;
  if (i < n) out[i] = Y[i];
  if (i == 0) out[n] = *lb_acc;
}

// ---------------------------------------------------------------------------
extern "C" void kernel_launch(void* const* d_in, const int* in_sizes, int n_in,
                              void* d_out, int out_size, void* d_ws, size_t ws_size,
                              hipStream_t stream) {
  const int*   ids   = (const int*)d_in[0];
  const float* enc   = (const float*)d_in[1];
  const int*   amask = (const int*)d_in[2];
  const float* emb   = (const float*)d_in[3];
  const float* pos   = (const float*)d_in[4];
  const float* sa_w  = (const float*)d_in[5];
  const float* sa_b  = (const float*)d_in[6];
  const float* ca_w  = (const float*)d_in[7];
  const float* ca_b  = (const float*)d_in[8];
  const float* ln_g  = (const float*)d_in[9];
  const float* ln_b  = (const float*)d_in[10];
  const float* rw    = (const float*)d_in[11];
  const float* rb    = (const float*)d_in[12];
  const float* ew1   = (const float*)d_in[13];
  const float* eb1   = (const float*)d_in[14];
  const float* ew2   = (const float*)d_in[15];
  const float* eb2   = (const float*)d_in[16];
  float* out = (float*)d_out;

  const size_t MD = (size_t)Mm * Dd;       // 1,048,576
  float* ws = (float*)d_ws;
  float* y    = ws;
  float* q    = ws + 1 * MD;
  float* k    = ws + 2 * MD;
  float* v    = ws + 3 * MD;
  float* att  = ws + 4 * MD;
  float* proj = ws + 5 * MD;
  float* Hbuf = ws + 6 * MD;                       // NP*FF = 8,388,608
  float* pout = Hbuf + (size_t)NPp * FFf;          // NP*D  = 2,097,152
  float* gates = pout + (size_t)NPp * Dd;          // M*2
  float* pair_gate = gates + (size_t)Mm * 2;       // NP
  float* sumP = pair_gate + NPp;                   // 8
  float* lb_acc = sumP + Ee;                       // 1
  int* ib = (int*)(lb_acc + 1);
  int* topi = ib;                 // M*2
  int* pair_tok = topi + Mm * 2;  // NP
  int* slot = pair_tok + NPp;     // NP
  int* cnt = slot + NPp;          // 8
  int* offs = cnt + Ee;           // 8
  int* fill = offs + Ee;          // 8

  init_lb_kernel<<<1, 64, 0, stream>>>(lb_acc);
  embed_kernel<<<Mm, 256, 0, stream>>>(ids, emb, pos, y);

  dim3 gProj(Dd / 64, Mm / 64);          // (8, 32)
  dim3 gAttn(Bb * Hh, Tt / 4);           // (16, 256)
  dim3 gE1(FFf / 64, NPp / 64, Ee);      // (32, 64, 8)
  dim3 gE2(Dd / 64, NPp / 64, Ee);       // (8, 64, 8)

  for (int i = 0; i < Ll; i++) {
    // ---- self-attention ----
    const float* w = sa_w + (size_t)i * 4 * DD_;
    const float* bqkv = sa_b + (size_t)i * 4 * Dd;
    gemm_bias<<<gProj, 256, 0, stream>>>(y, w + 0 * DD_, bqkv + 0 * Dd, q, Dd, Dd);
    gemm_bias<<<gProj, 256, 0, stream>>>(y, w + 1 * DD_, bqkv + 1 * Dd, k, Dd, Dd);
    gemm_bias<<<gProj, 256, 0, stream>>>(y, w + 2 * DD_, bqkv + 2 * Dd, v, Dd, Dd);
    attn_kernel<<<gAttn, 256, 0, stream>>>(q, k, v, att, amask, 1, Tt);
    gemm_bias<<<gProj, 256, 0, stream>>>(att, w + 3 * DD_, bqkv + 3 * Dd, proj, Dd, Dd);
    add_ln_kernel<<<Mm, 256, 0, stream>>>(y, proj, ln_g + (size_t)(i * 3 + 0) * Dd,
                                          ln_b + (size_t)(i * 3 + 0) * Dd);
    // ---- cross-attention ----
    const float* cw = ca_w + (size_t)i * 4 * DD_;
    const float* cb = ca_b + (size_t)i * 4 * Dd;
    gemm_bias<<<gProj, 256, 0, stream>>>(y, cw + 0 * DD_, cb + 0 * Dd, q, Dd, Dd);
    gemm_bias<<<gProj, 256, 0, stream>>>(enc, cw + 1 * DD_, cb + 1 * Dd, k, Dd, Dd);
    gemm_bias<<<gProj, 256, 0, stream>>>(enc, cw + 2 * DD_, cb + 2 * Dd, v, Dd, Dd);
    attn_kernel<<<gAttn, 256, 0, stream>>>(q, k, v, att, nullptr, 0, Ss);
    gemm_bias<<<gProj, 256, 0, stream>>>(att, cw + 3 * DD_, cb + 3 * Dd, proj, Dd, Dd);
    add_ln_kernel<<<Mm, 256, 0, stream>>>(y, proj, ln_g + (size_t)(i * 3 + 1) * Dd,
                                          ln_b + (size_t)(i * 3 + 1) * Dd);
    // ---- MoE ----
    zero_small_kernel<<<1, 64, 0, stream>>>(cnt, sumP);
    router_kernel<<<Mm / 4, 256, 0, stream>>>(y, rw + (size_t)i * Dd * Ee, rb + (size_t)i * Ee,
                                              gates, topi, cnt, sumP);
    prefix_lb_kernel<<<1, 64, 0, stream>>>(cnt, offs, fill, sumP, lb_acc);
    scatter_kernel<<<Mm / 256, 256, 0, stream>>>(topi, gates, offs, fill, pair_tok, pair_gate, slot);
    expert_gemm1<<<gE1, 256, 0, stream>>>(y, ew1 + (size_t)i * Ee * Dd * FFf,
                                          eb1 + (size_t)i * Ee * FFf, pair_tok, offs, cnt, Hbuf);
    expert_gemm2<<<gE2, 256, 0, stream>>>(Hbuf, ew2 + (size_t)i * Ee * FFf * Dd,
                                          eb2 + (size_t)i * Ee * Dd, pair_gate, offs, cnt, pout);
    combine_ln_kernel<<<Mm, 256, 0, stream>>>(y, pout, slot, ln_g + (size_t)(i * 3 + 2) * Dd,
                                              ln_b + (size_t)(i * 3 + 2) * Dd);
  }

  finalize_kernel<<<(int)((MD + 256) / 256) + 1, 256, 0, stream>>>(y, lb_acc, out);
}

// Round 4
// 3357.473 us; speedup vs baseline: 1.7795x; 1.7795x over previous
//
#include <hip/hip_runtime.h>
#include <math.h>

#define Bb 2
#define Tt 1024
#define Ss 1024
#define Dd 512
#define Hh 8
#define Ll 4
#define Ee 8
#define FFf 2048
#define Mm 2048
#define NPp 4096
#define EPSF 1e-5f
#define DD_ (Dd*Dd)
#define LOSC 1024.0f
#define ILOSC (1.0f/1024.0f)

typedef _Float16 f16;
typedef __attribute__((ext_vector_type(8))) _Float16 f16x8;
typedef __attribute__((ext_vector_type(4))) _Float16 f16x4;
typedef __attribute__((ext_vector_type(4))) float f32x4;

// split: x = hi + lo/1024 (lo pre-scaled by 1024 so it stays fp16-normal)
__device__ __forceinline__ void fsplit(float x, f16& h, f16& l) {
  h = (f16)x;
  l = (f16)((x - (float)h) * LOSC);
}

__device__ __forceinline__ void load16(const void* g, void* l) {
  __builtin_amdgcn_global_load_lds(
      (const __attribute__((address_space(1))) void*)g,
      (__attribute__((address_space(3))) void*)l, 16, 0, 0);
}

// ---------------------------------------------------------------------------
__global__ void embed_kernel(const int* __restrict__ ids,
                             const float* __restrict__ emb,
                             const float* __restrict__ pos,
                             float* __restrict__ Y,
                             f16* __restrict__ Yh, f16* __restrict__ Yl) {
  int m = blockIdx.x;
  int t = m % Tt;
  int id = ids[m];
  for (int d = threadIdx.x; d < Dd; d += 256) {
    float v = emb[(size_t)id * Dd + d] + pos[(size_t)t * Dd + d];
    Y[(size_t)m * Dd + d] = v;
    f16 h, l; fsplit(v, h, l);
    Yh[(size_t)m * Dd + d] = h;
    Yl[(size_t)m * Dd + d] = l;
  }
}

__global__ void cvt_split_kernel(const float* __restrict__ src,
                                 f16* __restrict__ dh, f16* __restrict__ dl) {
  size_t i = ((size_t)blockIdx.x * 256 + threadIdx.x) * 4;
  float4 v = *reinterpret_cast<const float4*>(&src[i]);
  float a[4] = {v.x, v.y, v.z, v.w};
#pragma unroll
  for (int j = 0; j < 4; j++) { f16 h, l; fsplit(a[j], h, l); dh[i + j] = h; dl[i + j] = l; }
}

// ---------------------------------------------------------------------------
// Batched transpose+split: src[z]=[Kd,Nd] fp32 -> dstH/dstL[z]=[Nd,Kd] fp16
// ---------------------------------------------------------------------------
__global__ __launch_bounds__(256)
void transpose_split(const float* __restrict__ src,
                     f16* __restrict__ dstH, f16* __restrict__ dstL,
                     int Kd, int Nd) {
  __shared__ float Tl[32][33];
  size_t zo = (size_t)blockIdx.z * Kd * Nd;
  int k0 = blockIdx.y * 32, n0 = blockIdx.x * 32;
  int t = threadIdx.x;
  int r = t >> 3, c = t & 7;
  float4 v = *reinterpret_cast<const float4*>(&src[zo + (size_t)(k0 + r) * Nd + n0 + c * 4]);
  Tl[r][c * 4 + 0] = v.x; Tl[r][c * 4 + 1] = v.y;
  Tl[r][c * 4 + 2] = v.z; Tl[r][c * 4 + 3] = v.w;
  __syncthreads();
  int nl = t >> 3, kq = t & 7;
  f16x4 hv, lv;
#pragma unroll
  for (int i = 0; i < 4; i++) {
    f16 h, l; fsplit(Tl[kq * 4 + i][nl], h, l);
    hv[i] = h; lv[i] = l;
  }
  size_t o = zo + (size_t)(n0 + nl) * Kd + k0 + kq * 4;
  *reinterpret_cast<f16x4*>(&dstH[o]) = hv;
  *reinterpret_cast<f16x4*>(&dstL[o]) = lv;
}

// ---------------------------------------------------------------------------
// 128x128 split-fp16 MFMA GEMM (3-product). A hi/lo [*,K], B hi/lo [N,K].
// ---------------------------------------------------------------------------
template <bool GATHER, bool OSPLIT, bool RELU, bool GATE>
__global__ __launch_bounds__(256)
void mm128(const f16* __restrict__ Ah_, const f16* __restrict__ Al_, int lda,
           const f16* __restrict__ Bh_, const f16* __restrict__ Bl_,
           const float* __restrict__ bias,
           float* __restrict__ Cf, f16* __restrict__ Ch, f16* __restrict__ Cl, int ldc,
           int Mtot, int N, int K,
           const int* __restrict__ tok, const float* __restrict__ gate,
           const int* __restrict__ offs, const int* __restrict__ cnt) {
  __shared__ f16 Ash[128 * 32];
  __shared__ f16 Asl[128 * 32];
  __shared__ f16 Bsh[128 * 32];
  __shared__ f16 Bsl[128 * 32];
  int e = blockIdx.z;
  int base = 0, ne = Mtot;
  if (offs) { base = offs[e]; ne = cnt[e]; }
  int m0 = blockIdx.y * 128;
  if (m0 >= ne) return;
  int rem = ne - m0;
  Bh_ += (size_t)e * N * K;
  Bl_ += (size_t)e * N * K;
  bias += (size_t)e * N;

  int t = threadIdx.x;
  int rr = t >> 2, cc = t & 3;
  int gr0 = base + m0 + rr;      if (gr0 > Mtot - 1) gr0 = Mtot - 1;
  int gr1 = base + m0 + rr + 64; if (gr1 > Mtot - 1) gr1 = Mtot - 1;
  int arow0 = GATHER ? tok[gr0] : gr0;
  int arow1 = GATHER ? tok[gr1] : gr1;
  size_t aoff0 = (size_t)arow0 * lda + cc * 8;
  size_t aoff1 = (size_t)arow1 * lda + cc * 8;
  size_t boff0 = (size_t)(blockIdx.x * 128 + rr) * K + cc * 8;
  size_t boff1 = (size_t)(blockIdx.x * 128 + rr + 64) * K + cc * 8;

  int lane = t & 63, wv = t >> 6;
  int quad = lane >> 4, m16 = lane & 15;
  int wm = (wv >> 1) * 64, wn = (wv & 1) * 64;

  f32x4 accm[4][4], accc[4][4];
#pragma unroll
  for (int i = 0; i < 4; i++)
#pragma unroll
    for (int j = 0; j < 4; j++) {
      accm[i][j] = (f32x4){0.f, 0.f, 0.f, 0.f};
      accc[i][j] = (f32x4){0.f, 0.f, 0.f, 0.f};
    }

  for (int kc = 0; kc < K; kc += 32) {
    load16(Ah_ + aoff0 + kc, &Ash[t * 8]);
    load16(Ah_ + aoff1 + kc, &Ash[2048 + t * 8]);
    load16(Al_ + aoff0 + kc, &Asl[t * 8]);
    load16(Al_ + aoff1 + kc, &Asl[2048 + t * 8]);
    load16(Bh_ + boff0 + kc, &Bsh[t * 8]);
    load16(Bh_ + boff1 + kc, &Bsh[2048 + t * 8]);
    load16(Bl_ + boff0 + kc, &Bsl[t * 8]);
    load16(Bl_ + boff1 + kc, &Bsl[2048 + t * 8]);
    __syncthreads();
    f16x8 ah[4], al[4];
#pragma unroll
    for (int i = 0; i < 4; i++) {
      ah[i] = *reinterpret_cast<const f16x8*>(&Ash[(wm + i * 16 + m16) * 32 + quad * 8]);
      al[i] = *reinterpret_cast<const f16x8*>(&Asl[(wm + i * 16 + m16) * 32 + quad * 8]);
    }
#pragma unroll
    for (int j = 0; j < 4; j++) {
      f16x8 bh = *reinterpret_cast<const f16x8*>(&Bsh[(wn + j * 16 + m16) * 32 + quad * 8]);
      f16x8 bl = *reinterpret_cast<const f16x8*>(&Bsl[(wn + j * 16 + m16) * 32 + quad * 8]);
#pragma unroll
      for (int i = 0; i < 4; i++) {
        accm[i][j] = __builtin_amdgcn_mfma_f32_16x16x32_f16(ah[i], bh, accm[i][j], 0, 0, 0);
        accc[i][j] = __builtin_amdgcn_mfma_f32_16x16x32_f16(ah[i], bl, accc[i][j], 0, 0, 0);
        accc[i][j] = __builtin_amdgcn_mfma_f32_16x16x32_f16(al[i], bh, accc[i][j], 0, 0, 0);
      }
    }
    __syncthreads();
  }

#pragma unroll
  for (int i = 0; i < 4; i++) {
#pragma unroll
    for (int reg = 0; reg < 4; reg++) {
      int lr = wm + i * 16 + quad * 4 + reg;
      if (lr < rem) {
        size_t grow = (size_t)(base + m0 + lr);
        float gv = 1.f;
        if (GATE) gv = gate[grow];
#pragma unroll
        for (int j = 0; j < 4; j++) {
          int col = blockIdx.x * 128 + wn + j * 16 + m16;
          float v = accm[i][j][reg] + accc[i][j][reg] * ILOSC + bias[col];
          if (RELU) v = fmaxf(v, 0.f);
          if (GATE) v *= gv;
          if (OSPLIT) {
            f16 h, l; fsplit(v, h, l);
            Ch[grow * ldc + col] = h;
            Cl[grow * ldc + col] = l;
          } else {
            Cf[grow * ldc + col] = v;
          }
        }
      }
    }
  }
}

// ---------------------------------------------------------------------------
// Split-fp16 MFMA flash attention. Wave = 16 queries, 32-key tiles.
// grid: (B*H, T/64)
// ---------------------------------------------------------------------------
__global__ __launch_bounds__(256)
void attn_mfma(const f16* __restrict__ Qh, const f16* __restrict__ Ql, int sq, int oq,
               const f16* __restrict__ Kh, const f16* __restrict__ Kl, int sk, int ok,
               const f16* __restrict__ Vh, const f16* __restrict__ Vl, int sv, int ov,
               f16* __restrict__ Oh, f16* __restrict__ Ol,
               const int* __restrict__ amask, int causal, int nK) {
  __shared__ f16 Ksh[32 * 64];
  __shared__ f16 Ksl[32 * 64];
  __shared__ f16 Vth[64 * 32];
  __shared__ f16 Vtl[64 * 32];
  __shared__ f16 Psh[4 * 16 * 32];
  __shared__ f16 Psl[4 * 16 * 32];

  int bh = blockIdx.x;
  int b = bh >> 3, hd = bh & 7;
  int t = threadIdx.x;
  int wv = t >> 6, lane = t & 63;
  int quad = lane >> 4, m16 = lane & 15;
  int qfrow = blockIdx.y * 64 + wv * 16 + m16;
  int qcbase = blockIdx.y * 64 + wv * 16 + quad * 4;

  size_t qoff = (size_t)(b * Tt + qfrow) * sq + oq + hd * 64;
  f16x8 qh0 = *reinterpret_cast<const f16x8*>(Qh + qoff + quad * 8);
  f16x8 qh1 = *reinterpret_cast<const f16x8*>(Qh + qoff + 32 + quad * 8);
  f16x8 ql0 = *reinterpret_cast<const f16x8*>(Ql + qoff + quad * 8);
  f16x8 ql1 = *reinterpret_cast<const f16x8*>(Ql + qoff + 32 + quad * 8);

  f32x4 Om[4], Oc[4];
#pragma unroll
  for (int c = 0; c < 4; c++) {
    Om[c] = (f32x4){0.f, 0.f, 0.f, 0.f};
    Oc[c] = (f32x4){0.f, 0.f, 0.f, 0.f};
  }
  float mr[4] = {-1e30f, -1e30f, -1e30f, -1e30f};
  float lrw[4] = {0.f, 0.f, 0.f, 0.f};

  int NT = causal ? (blockIdx.y * 2 + 2) : (nK >> 5);
  int myNT = causal ? (((blockIdx.y * 64 + wv * 16 + 15) >> 5) + 1) : NT;

  int rk = t >> 3, gs = t & 7, gsrc = gs ^ (rk & 7);
  int rv = t & 31, gv = t >> 5;

  for (int kt = 0; kt < NT; ++kt) {
    __syncthreads();
    {
      size_t krow = (size_t)(b * 1024 + kt * 32 + rk) * sk + ok + hd * 64 + gsrc * 8;
      *reinterpret_cast<f16x8*>(&Ksh[t * 8]) = *reinterpret_cast<const f16x8*>(Kh + krow);
      *reinterpret_cast<f16x8*>(&Ksl[t * 8]) = *reinterpret_cast<const f16x8*>(Kl + krow);
      size_t vrow = (size_t)(b * 1024 + kt * 32 + rv) * sv + ov + hd * 64 + gv * 8;
      f16x8 vh8 = *reinterpret_cast<const f16x8*>(Vh + vrow);
      f16x8 vl8 = *reinterpret_cast<const f16x8*>(Vl + vrow);
#pragma unroll
      for (int i = 0; i < 8; i++) {
        Vth[(gv * 8 + i) * 32 + rv] = vh8[i];
        Vtl[(gv * 8 + i) * 32 + rv] = vl8[i];
      }
    }
    __syncthreads();

    if (kt < myNT) {
      f32x4 S0m = (f32x4){0.f, 0.f, 0.f, 0.f}, S0c = S0m, S1m = S0m, S1c = S0m;
      {
        int key0 = m16, key1 = 16 + m16;
        int g0a = (quad) ^ (key0 & 7), g0b = (4 + quad) ^ (key0 & 7);
        int g1a = (quad) ^ (key1 & 7), g1b = (4 + quad) ^ (key1 & 7);
        f16x8 kh0a = *reinterpret_cast<const f16x8*>(&Ksh[key0 * 64 + g0a * 8]);
        f16x8 kh0b = *reinterpret_cast<const f16x8*>(&Ksh[key0 * 64 + g0b * 8]);
        f16x8 kl0a = *reinterpret_cast<const f16x8*>(&Ksl[key0 * 64 + g0a * 8]);
        f16x8 kl0b = *reinterpret_cast<const f16x8*>(&Ksl[key0 * 64 + g0b * 8]);
        S0m = __builtin_amdgcn_mfma_f32_16x16x32_f16(qh0, kh0a, S0m, 0, 0, 0);
        S0m = __builtin_amdgcn_mfma_f32_16x16x32_f16(qh1, kh0b, S0m, 0, 0, 0);
        S0c = __builtin_amdgcn_mfma_f32_16x16x32_f16(qh0, kl0a, S0c, 0, 0, 0);
        S0c = __builtin_amdgcn_mfma_f32_16x16x32_f16(qh1, kl0b, S0c, 0, 0, 0);
        S0c = __builtin_amdgcn_mfma_f32_16x16x32_f16(ql0, kh0a, S0c, 0, 0, 0);
        S0c = __builtin_amdgcn_mfma_f32_16x16x32_f16(ql1, kh0b, S0c, 0, 0, 0);
        f16x8 kh1a = *reinterpret_cast<const f16x8*>(&Ksh[key1 * 64 + g1a * 8]);
        f16x8 kh1b = *reinterpret_cast<const f16x8*>(&Ksh[key1 * 64 + g1b * 8]);
        f16x8 kl1a = *reinterpret_cast<const f16x8*>(&Ksl[key1 * 64 + g1a * 8]);
        f16x8 kl1b = *reinterpret_cast<const f16x8*>(&Ksl[key1 * 64 + g1b * 8]);
        S1m = __builtin_amdgcn_mfma_f32_16x16x32_f16(qh0, kh1a, S1m, 0, 0, 0);
        S1m = __builtin_amdgcn_mfma_f32_16x16x32_f16(qh1, kh1b, S1m, 0, 0, 0);
        S1c = __builtin_amdgcn_mfma_f32_16x16x32_f16(qh0, kl1a, S1c, 0, 0, 0);
        S1c = __builtin_amdgcn_mfma_f32_16x16x32_f16(qh1, kl1b, S1c, 0, 0, 0);
        S1c = __builtin_amdgcn_mfma_f32_16x16x32_f16(ql0, kh1a, S1c, 0, 0, 0);
        S1c = __builtin_amdgcn_mfma_f32_16x16x32_f16(ql1, kh1b, S1c, 0, 0, 0);
      }
      float S0[4], S1[4];
      int key0 = kt * 32 + m16, key1 = kt * 32 + 16 + m16;
      int am0 = amask ? amask[b * nK + key0] : 1;
      int am1 = amask ? amask[b * nK + key1] : 1;
#pragma unroll
      for (int reg = 0; reg < 4; reg++) {
        int qr = qcbase + reg;
        bool ok0 = am0 && (!causal || key0 <= qr);
        bool ok1 = am1 && (!causal || key1 <= qr);
        S0[reg] = ok0 ? (S0m[reg] + S0c[reg] * ILOSC) * 0.125f : -1e9f;
        S1[reg] = ok1 ? (S1m[reg] + S1c[reg] * ILOSC) * 0.125f : -1e9f;
      }
      float mt[4], al4[4], rs[4];
#pragma unroll
      for (int reg = 0; reg < 4; reg++) mt[reg] = fmaxf(S0[reg], S1[reg]);
#pragma unroll
      for (int off = 1; off < 16; off <<= 1)
#pragma unroll
        for (int reg = 0; reg < 4; reg++) mt[reg] = fmaxf(mt[reg], __shfl_xor(mt[reg], off, 64));
#pragma unroll
      for (int reg = 0; reg < 4; reg++) {
        float mn = fmaxf(mr[reg], mt[reg]);
        al4[reg] = expf(mr[reg] - mn);
        mr[reg] = mn;
        S0[reg] = expf(S0[reg] - mn);
        S1[reg] = expf(S1[reg] - mn);
        rs[reg] = S0[reg] + S1[reg];
      }
#pragma unroll
      for (int off = 1; off < 16; off <<= 1)
#pragma unroll
        for (int reg = 0; reg < 4; reg++) rs[reg] += __shfl_xor(rs[reg], off, 64);
#pragma unroll
      for (int reg = 0; reg < 4; reg++) {
        lrw[reg] = lrw[reg] * al4[reg] + rs[reg];
#pragma unroll
        for (int c = 0; c < 4; c++) { Om[c][reg] *= al4[reg]; Oc[c][reg] *= al4[reg]; }
        int prow = wv * 16 + quad * 4 + reg;
        f16 ph, pl;
        fsplit(S0[reg], ph, pl);
        Psh[prow * 32 + m16] = ph; Psl[prow * 32 + m16] = pl;
        fsplit(S1[reg], ph, pl);
        Psh[prow * 32 + 16 + m16] = ph; Psl[prow * 32 + 16 + m16] = pl;
      }
      __builtin_amdgcn_sched_barrier(0);
      f16x8 pah = *reinterpret_cast<const f16x8*>(&Psh[(wv * 16 + m16) * 32 + quad * 8]);
      f16x8 pal = *reinterpret_cast<const f16x8*>(&Psl[(wv * 16 + m16) * 32 + quad * 8]);
#pragma unroll
      for (int c = 0; c < 4; c++) {
        f16x8 vbh = *reinterpret_cast<const f16x8*>(&Vth[(c * 16 + m16) * 32 + quad * 8]);
        f16x8 vbl = *reinterpret_cast<const f16x8*>(&Vtl[(c * 16 + m16) * 32 + quad * 8]);
        Om[c] = __builtin_amdgcn_mfma_f32_16x16x32_f16(pah, vbh, Om[c], 0, 0, 0);
        Oc[c] = __builtin_amdgcn_mfma_f32_16x16x32_f16(pah, vbl, Oc[c], 0, 0, 0);
        Oc[c] = __builtin_amdgcn_mfma_f32_16x16x32_f16(pal, vbh, Oc[c], 0, 0, 0);
      }
    }
  }
#pragma unroll
  for (int reg = 0; reg < 4; reg++) {
    int qr = qcbase + reg;
    float inv = 1.f / lrw[reg];
#pragma unroll
    for (int c = 0; c < 4; c++) {
      float o = (Om[c][reg] + Oc[c][reg] * ILOSC) * inv;
      f16 hh, ll; fsplit(o, hh, ll);
      size_t oo = (size_t)(b * Tt + qr) * Dd + hd * 64 + c * 16 + m16;
      Oh[oo] = hh;
      Ol[oo] = ll;
    }
  }
}

// ---------------------------------------------------------------------------
__global__ __launch_bounds__(256)
void add_ln_kernel(float* __restrict__ Y, f16* __restrict__ Yh, f16* __restrict__ Yl,
                   const float* __restrict__ Aadd,
                   const float* __restrict__ g, const float* __restrict__ bb) {
  int tid = threadIdx.x;
  size_t base = (size_t)blockIdx.x * Dd;
  __shared__ float red[256];
  __shared__ float mu_s, rs_s;
  float x0 = Y[base + tid] + Aadd[base + tid];
  float x1 = Y[base + 256 + tid] + Aadd[base + 256 + tid];
  red[tid] = x0 + x1; __syncthreads();
  for (int s2 = 128; s2 > 0; s2 >>= 1) { if (tid < s2) red[tid] += red[tid + s2]; __syncthreads(); }
  if (tid == 0) mu_s = red[0] / (float)Dd;
  __syncthreads();
  float mu = mu_s;
  float d0 = x0 - mu, d1 = x1 - mu;
  red[tid] = d0 * d0 + d1 * d1; __syncthreads();
  for (int s2 = 128; s2 > 0; s2 >>= 1) { if (tid < s2) red[tid] += red[tid + s2]; __syncthreads(); }
  if (tid == 0) rs_s = rsqrtf(red[0] / (float)Dd + EPSF);
  __syncthreads();
  float rs = rs_s;
  float o0 = d0 * rs * g[tid] + bb[tid];
  float o1 = d1 * rs * g[256 + tid] + bb[256 + tid];
  f16 h, l;
  Y[base + tid] = o0; fsplit(o0, h, l); Yh[base + tid] = h; Yl[base + tid] = l;
  Y[base + 256 + tid] = o1; fsplit(o1, h, l); Yh[base + 256 + tid] = h; Yl[base + 256 + tid] = l;
}

__global__ __launch_bounds__(256)
void combine_ln_kernel(float* __restrict__ Y, f16* __restrict__ Yh, f16* __restrict__ Yl,
                       const float* __restrict__ pout, const int* __restrict__ slot,
                       const float* __restrict__ g, const float* __restrict__ bb) {
  int tid = threadIdx.x;
  int m = blockIdx.x;
  size_t base = (size_t)m * Dd;
  int s0 = slot[m * 2 + 0], s1 = slot[m * 2 + 1];
  __shared__ float red[256];
  __shared__ float mu_s, rs_s;
  float x0 = Y[base + tid] + pout[(size_t)s0 * Dd + tid] + pout[(size_t)s1 * Dd + tid];
  float x1 = Y[base + 256 + tid] + pout[(size_t)s0 * Dd + 256 + tid] + pout[(size_t)s1 * Dd + 256 + tid];
  red[tid] = x0 + x1; __syncthreads();
  for (int s2 = 128; s2 > 0; s2 >>= 1) { if (tid < s2) red[tid] += red[tid + s2]; __syncthreads(); }
  if (tid == 0) mu_s = red[0] / (float)Dd;
  __syncthreads();
  float mu = mu_s;
  float d0 = x0 - mu, d1 = x1 - mu;
  red[tid] = d0 * d0 + d1 * d1; __syncthreads();
  for (int s2 = 128; s2 > 0; s2 >>= 1) { if (tid < s2) red[tid] += red[tid + s2]; __syncthreads(); }
  if (tid == 0) rs_s = rsqrtf(red[0] / (float)Dd + EPSF);
  __syncthreads();
  float rs = rs_s;
  float o0 = d0 * rs * g[tid] + bb[tid];
  float o1 = d1 * rs * g[256 + tid] + bb[256 + tid];
  f16 h, l;
  Y[base + tid] = o0; fsplit(o0, h, l); Yh[base + tid] = h; Yl[base + tid] = l;
  Y[base + 256 + tid] = o1; fsplit(o1, h, l); Yh[base + 256 + tid] = h; Yl[base + 256 + tid] = l;
}

// ---------------------------------------------------------------------------
__global__ void zero_small_kernel(int* cnt, float* sumP) {
  int t = threadIdx.x;
  if (t < Ee) { cnt[t] = 0; sumP[t] = 0.f; }
}

__global__ __launch_bounds__(256)
void router_kernel(const float* __restrict__ Y, const float* __restrict__ rw,
                   const float* __restrict__ rb, float* __restrict__ gates,
                   int* __restrict__ topi, int* __restrict__ cnt,
                   float* __restrict__ sumP) {
  int wv = threadIdx.x >> 6, lane = threadIdx.x & 63;
  int m = blockIdx.x * 4 + wv;
  const float* yr = Y + (size_t)m * Dd;
  float acc[Ee];
#pragma unroll
  for (int e = 0; e < Ee; e++) acc[e] = 0.f;
  for (int d = lane; d < Dd; d += 64) {
    float yv = yr[d];
#pragma unroll
    for (int e = 0; e < Ee; e++) acc[e] += yv * rw[d * Ee + e];
  }
#pragma unroll
  for (int e = 0; e < Ee; e++)
    for (int off = 32; off; off >>= 1) acc[e] += __shfl_xor(acc[e], off, 64);
  if (lane == 0) {
    float pv[Ee];
    float mx = -1e30f;
    for (int e = 0; e < Ee; e++) { pv[e] = acc[e] + rb[e]; mx = fmaxf(mx, pv[e]); }
    float ssum = 0.f;
    for (int e = 0; e < Ee; e++) { pv[e] = expf(pv[e] - mx); ssum += pv[e]; }
    for (int e = 0; e < Ee; e++) pv[e] /= ssum;
    int i1 = 0;
    for (int e = 1; e < Ee; e++) if (pv[e] > pv[i1]) i1 = e;
    int i2 = (i1 == 0) ? 1 : 0;
    for (int e = 0; e < Ee; e++) if (e != i1 && pv[e] > pv[i2]) i2 = e;
    float gs = pv[i1] + pv[i2];
    gates[m * 2 + 0] = pv[i1] / gs;
    gates[m * 2 + 1] = pv[i2] / gs;
    topi[m * 2 + 0] = i1;
    topi[m * 2 + 1] = i2;
    atomicAdd(&cnt[i1], 1);
    atomicAdd(&cnt[i2], 1);
    for (int e = 0; e < Ee; e++) atomicAdd(&sumP[e], pv[e]);
  }
}

__global__ void prefix_lb_kernel(const int* __restrict__ cnt, int* __restrict__ offs,
                                 int* __restrict__ fill, const float* __restrict__ sumP,
                                 float* __restrict__ lb_acc) {
  if (threadIdx.x == 0) {
    int run = 0;
    float lb = 0.f;
    for (int e = 0; e < Ee; e++) {
      offs[e] = run; run += cnt[e];
      fill[e] = 0;
      lb += ((float)cnt[e] / (float)Mm) * (sumP[e] / (float)Mm);
    }
    *lb_acc += (float)Ee * lb;
  }
}

__global__ __launch_bounds__(256)
void scatter_kernel(const int* __restrict__ topi, const float* __restrict__ gates,
                    const int* __restrict__ offs, int* __restrict__ fill,
                    int* __restrict__ pair_tok, float* __restrict__ pair_gate,
                    int* __restrict__ slot) {
  int m = blockIdx.x * 256 + threadIdx.x;
  if (m >= Mm) return;
  for (int k2 = 0; k2 < 2; k2++) {
    int e = topi[m * 2 + k2];
    int pos = atomicAdd(&fill[e], 1);
    int idx = offs[e] + pos;
    pair_tok[idx] = m;
    pair_gate[idx] = gates[m * 2 + k2];
    slot[m * 2 + k2] = idx;
  }
}

__global__ void init_lb_kernel(float* lb_acc) {
  if (threadIdx.x == 0) *lb_acc = 0.f;
}

__global__ void finalize_kernel(const float* __restrict__ Y,
                                const float* __restrict__ lb_acc,
                                float* __restrict__ out) {
  size_t i = (size_t)blockIdx.x * 256 + threadIdx.x;
  const size_t n = (size_t)Mm * Dd;
  if (i < n) out[i] = Y[i];
  if (i == 0) out[n] = *lb_acc;
}

// ---------------------------------------------------------------------------
extern "C" void kernel_launch(void* const* d_in, const int* in_sizes, int n_in,
                              void* d_out, int out_size, void* d_ws, size_t ws_size,
                              hipStream_t stream) {
  const int*   ids   = (const int*)d_in[0];
  const float* enc   = (const float*)d_in[1];
  const int*   amask = (const int*)d_in[2];
  const float* emb   = (const float*)d_in[3];
  const float* pos   = (const float*)d_in[4];
  const float* sa_w  = (const float*)d_in[5];
  const float* sa_b  = (const float*)d_in[6];
  const float* ca_w  = (const float*)d_in[7];
  const float* ca_b  = (const float*)d_in[8];
  const float* ln_g  = (const float*)d_in[9];
  const float* ln_b  = (const float*)d_in[10];
  const float* rw    = (const float*)d_in[11];
  const float* rb    = (const float*)d_in[12];
  const float* ew1   = (const float*)d_in[13];
  const float* eb1   = (const float*)d_in[14];
  const float* ew2   = (const float*)d_in[15];
  const float* eb2   = (const float*)d_in[16];
  float* out = (float*)d_out;

  char* p = (char*)d_ws;
  auto alloc = [&](size_t bytes) { void* r = p; p += (bytes + 255) & ~(size_t)255; return r; };
  float* y    = (float*)alloc((size_t)Mm * Dd * 4);
  float* proj = (float*)alloc((size_t)Mm * Dd * 4);
  float* pout = (float*)alloc((size_t)NPp * Dd * 4);
  f16* yh   = (f16*)alloc((size_t)Mm * Dd * 2);
  f16* yl   = (f16*)alloc((size_t)Mm * Dd * 2);
  f16* ench = (f16*)alloc((size_t)Mm * Dd * 2);
  f16* encl = (f16*)alloc((size_t)Mm * Dd * 2);
  f16* qkvh = (f16*)alloc((size_t)Mm * 1536 * 2);
  f16* qkvl = (f16*)alloc((size_t)Mm * 1536 * 2);
  f16* qch  = (f16*)alloc((size_t)Mm * Dd * 2);
  f16* qcl  = (f16*)alloc((size_t)Mm * Dd * 2);
  f16* atth = (f16*)alloc((size_t)Mm * Dd * 2);
  f16* attl = (f16*)alloc((size_t)Mm * Dd * 2);
  f16* ckvh = (f16*)alloc((size_t)Mm * 1024 * 2);
  f16* ckvl = (f16*)alloc((size_t)Mm * 1024 * 2);
  f16* moeh = (f16*)alloc((size_t)NPp * FFf * 2);
  f16* moel = (f16*)alloc((size_t)NPp * FFf * 2);
  f16* saTh = (f16*)alloc((size_t)Ll * 4 * DD_ * 2);
  f16* saTl = (f16*)alloc((size_t)Ll * 4 * DD_ * 2);
  f16* caTh = (f16*)alloc((size_t)Ll * 4 * DD_ * 2);
  f16* caTl = (f16*)alloc((size_t)Ll * 4 * DD_ * 2);
  f16* w1Th = (f16*)alloc((size_t)Ee * Dd * FFf * 2);
  f16* w1Tl = (f16*)alloc((size_t)Ee * Dd * FFf * 2);
  f16* w2Th = (f16*)alloc((size_t)Ee * Dd * FFf * 2);
  f16* w2Tl = (f16*)alloc((size_t)Ee * Dd * FFf * 2);
  float* gates     = (float*)alloc((size_t)Mm * 2 * 4);
  float* pair_gate = (float*)alloc((size_t)NPp * 4);
  float* sumP      = (float*)alloc(Ee * 4);
  float* lb_acc    = (float*)alloc(4);
  int* topi     = (int*)alloc((size_t)Mm * 2 * 4);
  int* pair_tok = (int*)alloc((size_t)NPp * 4);
  int* slot     = (int*)alloc((size_t)Mm * 2 * 4);
  int* cnt      = (int*)alloc(Ee * 4);
  int* offs     = (int*)alloc(Ee * 4);
  int* fill     = (int*)alloc(Ee * 4);

  init_lb_kernel<<<1, 64, 0, stream>>>(lb_acc);
  embed_kernel<<<Mm, 256, 0, stream>>>(ids, emb, pos, y, yh, yl);
  cvt_split_kernel<<<(Mm * Dd) / 1024, 256, 0, stream>>>(enc, ench, encl);
  transpose_split<<<dim3(16, 16, 16), 256, 0, stream>>>(sa_w, saTh, saTl, Dd, Dd);
  transpose_split<<<dim3(16, 16, 16), 256, 0, stream>>>(ca_w, caTh, caTl, Dd, Dd);

  dim3 gAttn(Bb * Hh, Tt / 64);

  for (int i = 0; i < Ll; i++) {
    transpose_split<<<dim3(64, 16, 8), 256, 0, stream>>>(ew1 + (size_t)i * Ee * Dd * FFf, w1Th, w1Tl, Dd, FFf);
    transpose_split<<<dim3(16, 64, 8), 256, 0, stream>>>(ew2 + (size_t)i * Ee * FFf * Dd, w2Th, w2Tl, FFf, Dd);

    const f16* saThl = saTh + (size_t)i * 4 * DD_;
    const f16* saTll = saTl + (size_t)i * 4 * DD_;
    const f16* caThl = caTh + (size_t)i * 4 * DD_;
    const f16* caTll = caTl + (size_t)i * 4 * DD_;
    const float* sabl = sa_b + (size_t)i * 4 * Dd;
    const float* cabl = ca_b + (size_t)i * 4 * Dd;

    // cross K,V (fused N=1024)
    mm128<false, true, false, false><<<dim3(8, 16, 1), 256, 0, stream>>>(
        ench, encl, Dd, caThl + DD_, caTll + DD_, cabl + Dd,
        nullptr, ckvh, ckvl, 1024, Mm, 1024, Dd, nullptr, nullptr, nullptr, nullptr);
    // self QKV (fused N=1536)
    mm128<false, true, false, false><<<dim3(12, 16, 1), 256, 0, stream>>>(
        yh, yl, Dd, saThl, saTll, sabl,
        nullptr, qkvh, qkvl, 1536, Mm, 1536, Dd, nullptr, nullptr, nullptr, nullptr);
    // self attention
    attn_mfma<<<gAttn, 256, 0, stream>>>(qkvh, qkvl, 1536, 0, qkvh, qkvl, 1536, 512,
                                         qkvh, qkvl, 1536, 1024, atth, attl, amask, 1, Tt);
    // self out-proj
    mm128<false, false, false, false><<<dim3(4, 16, 1), 256, 0, stream>>>(
        atth, attl, Dd, saThl + 3 * DD_, saTll + 3 * DD_, sabl + 3 * Dd,
        proj, nullptr, nullptr, Dd, Mm, Dd, Dd, nullptr, nullptr, nullptr, nullptr);
    add_ln_kernel<<<Mm, 256, 0, stream>>>(y, yh, yl, proj,
                                          ln_g + (size_t)(i * 3 + 0) * Dd, ln_b + (size_t)(i * 3 + 0) * Dd);
    // cross Q
    mm128<false, true, false, false><<<dim3(4, 16, 1), 256, 0, stream>>>(
        yh, yl, Dd, caThl, caTll, cabl,
        nullptr, qch, qcl, Dd, Mm, Dd, Dd, nullptr, nullptr, nullptr, nullptr);
    // cross attention
    attn_mfma<<<gAttn, 256, 0, stream>>>(qch, qcl, Dd, 0, ckvh, ckvl, 1024, 0,
                                         ckvh, ckvl, 1024, 512, atth, attl, nullptr, 0, Ss);
    // cross out-proj
    mm128<false, false, false, false><<<dim3(4, 16, 1), 256, 0, stream>>>(
        atth, attl, Dd, caThl + 3 * DD_, caTll + 3 * DD_, cabl + 3 * Dd,
        proj, nullptr, nullptr, Dd, Mm, Dd, Dd, nullptr, nullptr, nullptr, nullptr);
    add_ln_kernel<<<Mm, 256, 0, stream>>>(y, yh, yl, proj,
                                          ln_g + (size_t)(i * 3 + 1) * Dd, ln_b + (size_t)(i * 3 + 1) * Dd);
    // MoE
    zero_small_kernel<<<1, 64, 0, stream>>>(cnt, sumP);
    router_kernel<<<Mm / 4, 256, 0, stream>>>(y, rw + (size_t)i * Dd * Ee, rb + (size_t)i * Ee,
                                              gates, topi, cnt, sumP);
    prefix_lb_kernel<<<1, 64, 0, stream>>>(cnt, offs, fill, sumP, lb_acc);
    scatter_kernel<<<Mm / 256, 256, 0, stream>>>(topi, gates, offs, fill, pair_tok, pair_gate, slot);
    mm128<true, true, true, false><<<dim3(16, 32, 8), 256, 0, stream>>>(
        yh, yl, Dd, w1Th, w1Tl, eb1 + (size_t)i * Ee * FFf,
        nullptr, moeh, moel, FFf, NPp, FFf, Dd, pair_tok, nullptr, offs, cnt);
    mm128<false, false, false, true><<<dim3(4, 32, 8), 256, 0, stream>>>(
        moeh, moel, FFf, w2Th, w2Tl, eb2 + (size_t)i * Ee * Dd,
        pout, nullptr, nullptr, Dd, NPp, Dd, FFf, nullptr, pair_gate, offs, cnt);
    combine_ln_kernel<<<Mm, 256, 0, stream>>>(y, yh, yl, pout, slot,
                                              ln_g + (size_t)(i * 3 + 2) * Dd, ln_b + (size_t)(i * 3 + 2) * Dd);
  }

  finalize_kernel<<<(int)(((size_t)Mm * Dd + 256) / 256) + 1, 256, 0, stream>>>(y, lb_acc, out);
}